// Round 19
// baseline (71.407 us; speedup 1.0000x reference)
//
#include <hip/hip_runtime.h>
#include <math.h>

// Problem constants
#define QDIM 512     // 2^9 state dim
#define DD   128     // K*C_IN = input dim of quadratic form
#define LIN  4096
#define LOUT 4089    // (4096 - 7 - 1)/1 + 1
#define NC   16      // C_IN
#define NB   16      // batch

typedef __attribute__((ext_vector_type(8))) short bf16x8;
typedef __attribute__((ext_vector_type(4))) float f32x4;

// Scratch in device globals (NOT d_ws) — R5 lesson. Every element rewritten
// each call before read. R8+R11: no grid barriers. R16/R17 lessons:
// per-block private byte streams are the wall; stage shared operands in LDS.
// Node overhead ~9-10us each -> 4-node chain is structural for this algebra.
__device__ float  g_B[QDIM * DD];          // W1 f32
__device__ float  g_C[QDIM * DD];          // W2 f32
__device__ unsigned short g_Ah[QDIM * DD]; // A bf16 hi (row-major [i][j])
__device__ unsigned short g_Al[QDIM * DD]; // A bf16 residual

// ---- bf16 helpers (RNE) ----
__device__ __forceinline__ unsigned short f2bf(float f) {
  union { float f; unsigned u; } v; v.f = f;
  unsigned u = v.u + 0x7FFFu + ((v.u >> 16) & 1u);
  return (unsigned short)(u >> 16);
}
__device__ __forceinline__ float bf2f(unsigned short h) {
  union { unsigned u; float f; } v; v.u = ((unsigned)h) << 16;
  return v.f;
}

// ---------------------------------------------------------------------------
// Precompute (verbatim R17/R18, measured-good).
// ---------------------------------------------------------------------------
__device__ __forceinline__ void butterfly_T(float* col, const float* theta,
                                            int l, int p) {
  #pragma unroll
  for (int qq = 0; qq < 9; ++qq) {
    int q = 8 - qq;                    // reverse order for transpose
    float half = theta[l * 9 + q] * 0.5f;
    float c = cosf(half), s = sinf(half);
    int right = QDIM >> (q + 1);
    int a = p >> (8 - q);
    int r = p & (right - 1);
    int i0 = (a * 2) * right + r;
    int i1 = i0 + right;
    float v0 = col[i0], v1 = col[i1];
    col[i0] = c * v0 + s * v1;         // transposed 2x2
    col[i1] = c * v1 - s * v0;
    __syncthreads();
  }
}

// W1[i][j] = (R1^T e_i)[j], j<128  -> g_B
__global__ __launch_bounds__(256) void w1_kernel(const float* __restrict__ E,
                                                 const float* __restrict__ theta) {
  __shared__ float erow[QDIM];
  int i = blockIdx.x;
  int p = threadIdx.x;
  erow[p]       = E[i * QDIM + p];
  erow[p + 256] = E[i * QDIM + p + 256];
  __syncthreads();
  butterfly_T(erow, theta, 0, p);
  if (p < DD) g_B[i * DD + p] = erow[p];
}

// W2[i][:] = (R2^T e_i)^T * W1   (g_B -> g_C)
__global__ __launch_bounds__(256) void mm1_kernel(const float* __restrict__ E,
                                                  const float* __restrict__ theta) {
  __shared__ float erow[QDIM];
  __shared__ float part[DD];
  int i = blockIdx.x;
  int tid = threadIdx.x;
  erow[tid]       = E[i * QDIM + tid];
  erow[tid + 256] = E[i * QDIM + tid + 256];
  __syncthreads();
  butterfly_T(erow, theta, 1, tid);

  int j = tid & 127, h = tid >> 7;
  float a0 = 0.f, a1 = 0.f, a2 = 0.f, a3 = 0.f;
  int m0 = h * 256;
  #pragma unroll 8
  for (int m = m0; m < m0 + 256; m += 4) {
    a0 = fmaf(erow[m + 0], g_B[(m + 0) * DD + j], a0);
    a1 = fmaf(erow[m + 1], g_B[(m + 1) * DD + j], a1);
    a2 = fmaf(erow[m + 2], g_B[(m + 2) * DD + j], a2);
    a3 = fmaf(erow[m + 3], g_B[(m + 3) * DD + j], a3);
  }
  float sum = (a0 + a1) + (a2 + a3);
  if (h == 1) part[j] = sum;
  __syncthreads();
  if (h == 0) g_C[i * DD + j] = sum + part[j];
}

// A[i][:] = (R3^T e_i)^T * W2   (g_C -> g_Ah/g_Al, bf16 split)
__global__ __launch_bounds__(256) void mm2_kernel(const float* __restrict__ E,
                                                  const float* __restrict__ theta) {
  __shared__ float erow[QDIM];
  __shared__ float part[DD];
  int i = blockIdx.x;
  int tid = threadIdx.x;
  erow[tid]       = E[i * QDIM + tid];
  erow[tid + 256] = E[i * QDIM + tid + 256];
  __syncthreads();
  butterfly_T(erow, theta, 2, tid);

  int j = tid & 127, h = tid >> 7;
  float a0 = 0.f, a1 = 0.f, a2 = 0.f, a3 = 0.f;
  int m0 = h * 256;
  #pragma unroll 8
  for (int m = m0; m < m0 + 256; m += 4) {
    a0 = fmaf(erow[m + 0], g_C[(m + 0) * DD + j], a0);
    a1 = fmaf(erow[m + 1], g_C[(m + 1) * DD + j], a1);
    a2 = fmaf(erow[m + 2], g_C[(m + 2) * DD + j], a2);
    a3 = fmaf(erow[m + 3], g_C[(m + 3) * DD + j], a3);
  }
  float sum = (a0 + a1) + (a2 + a3);
  if (h == 1) part[j] = sum;
  __syncthreads();
  if (h == 0) {
    sum += part[j];
    unsigned short hi = f2bf(sum);
    unsigned short lo = f2bf(sum - bf2f(hi));
    g_Ah[i * DD + j] = hi;
    g_Al[i * DD + j] = lo;
  }
}

// ---------------------------------------------------------------------------
// quadA v3: out[b,t] = sum_i sgn(i) (A v)_i^2 / (v^T v + eps).
// t-tile = 128 (512 blocks, 2/CU): halves chip-wide A L2-traffic vs R18
// (128MB ~ 3.7us floor); staging amortized over 2x MFMA. 4 waves x 32
// t-rows (2 m-tiles of 16). A staged in LDS in 8 chunks of 64 i-rows
// (hi+lo = 32KB), XOR-swizzled (G4). Per-t math order identical to R18
// -> absmax canary 9.765625e-4.
// ---------------------------------------------------------------------------
__global__ __launch_bounds__(256, 2) void quadA_kernel(const float* __restrict__ x,
                                                       float* __restrict__ out) {
  __shared__ float xs[NC][136];                // 135 used (128 t + 7 halo)
  __shared__ unsigned short sh_h[64 * DD];     // 16 KB, swizzled
  __shared__ unsigned short sh_l[64 * DD];     // 16 KB, swizzled
  int b = blockIdx.x;
  int t0 = blockIdx.y * 128;
  int tid = threadIdx.x;
  int lane = tid & 63;
  int w = tid >> 6;                            // wave: t-rows [w*32, w*32+32)
  const float* xb = x + (size_t)b * NC * LIN;

  for (int idx = tid; idx < NC * 135; idx += 256) {
    int c = idx / 135, o = idx % 135;
    int g = t0 + o;
    xs[c][o] = (g < LIN) ? xb[c * LIN + g] : 0.0f;
  }
  __syncthreads();

  int lrow = lane & 15;
  int lgrp = lane >> 4;

  // a-frags (2 m-tiles x 4 k-blocks) + ||v||^2 partials (R18 math order)
  bf16x8 a_hi[2][4], a_lo[2][4];
  float pn[2];
  #pragma unroll
  for (int m = 0; m < 2; ++m) {
    float s2 = 0.f;
    int tl = w * 32 + m * 16 + lrow;
    #pragma unroll
    for (int kb = 0; kb < 4; ++kb) {
      int c = kb * 4 + lgrp;
      #pragma unroll
      for (int e = 0; e < 8; ++e) {
        float v = xs[c][tl + e];
        unsigned short hh = f2bf(v);
        unsigned short ll = f2bf(v - bf2f(hh));
        a_hi[m][kb][e] = (short)hh;
        a_lo[m][kb][e] = (short)ll;
        s2 = fmaf(v, v, s2);
      }
    }
    s2 += __shfl_xor(s2, 16);
    s2 += __shfl_xor(s2, 32);
    pn[m] = s2;
  }

  float pd[2][4] = {{0.f,0.f,0.f,0.f},{0.f,0.f,0.f,0.f}};

  #pragma unroll 1
  for (int ch = 0; ch < 8; ++ch) {
    __syncthreads();                           // prior chunk reads complete
    // stage 64 i-rows (hi+lo), XOR swizzle: u16col ^= (row&7)<<3
    #pragma unroll
    for (int it = 0; it < 4; ++it) {
      int flat = it * 256 + tid;               // 1024 granules of 8 u16
      int row = flat >> 4;                     // 0..63
      int g8 = flat & 15;                      // granule within row
      int gidx = (ch * 64 + row) * DD + g8 * 8;
      int lidx = row * DD + ((g8 * 8) ^ ((row & 7) << 3));
      *(bf16x8*)&sh_h[lidx] = *(const bf16x8*)(g_Ah + gidx);
      *(bf16x8*)&sh_l[lidx] = *(const bf16x8*)(g_Al + gidx);
    }
    __syncthreads();

    #pragma unroll
    for (int nn = 0; nn < 4; ++nn) {           // i-tile: i = (ch*4+nn)*16 + lrow
      int rowc = nn * 16 + lrow;
      int swz = (rowc & 7) << 3;
      f32x4 acc[2];
      #pragma unroll
      for (int m = 0; m < 2; ++m) acc[m] = (f32x4){0.f, 0.f, 0.f, 0.f};
      #pragma unroll
      for (int kb = 0; kb < 4; ++kb) {
        int u16i = rowc * DD + ((kb * 32 + lgrp * 8) ^ swz);
        bf16x8 b_hi = *(const bf16x8*)&sh_h[u16i];
        bf16x8 b_lo = *(const bf16x8*)&sh_l[u16i];
        #pragma unroll
        for (int m = 0; m < 2; ++m) {
          acc[m] = __builtin_amdgcn_mfma_f32_16x16x32_bf16(a_hi[m][kb], b_hi, acc[m], 0, 0, 0);
          acc[m] = __builtin_amdgcn_mfma_f32_16x16x32_bf16(a_hi[m][kb], b_lo, acc[m], 0, 0, 0);
          acc[m] = __builtin_amdgcn_mfma_f32_16x16x32_bf16(a_lo[m][kb], b_hi, acc[m], 0, 0, 0);
        }
      }
      float sg = (ch * 4 + nn < 16) ? 1.0f : -1.0f;   // i<256
      #pragma unroll
      for (int m = 0; m < 2; ++m)
        #pragma unroll
        for (int r = 0; r < 4; ++r)
          pd[m][r] = fmaf(sg * acc[m][r], acc[m][r], pd[m][r]);
    }
  }

  // reduce pd over the 16 i-lanes; fetch pn for the C-frag's t-row
  #pragma unroll
  for (int m = 0; m < 2; ++m)
    #pragma unroll
    for (int r = 0; r < 4; ++r) {
      #pragma unroll
      for (int msk = 1; msk < 16; msk <<= 1)
        pd[m][r] += __shfl_xor(pd[m][r], msk);
    }
  float pnv[2][4];
  #pragma unroll
  for (int m = 0; m < 2; ++m)
    #pragma unroll
    for (int r = 0; r < 4; ++r)
      pnv[m][r] = __shfl(pn[m], lgrp * 4 + r);   // all lanes active

  if (lrow == 0) {
    #pragma unroll
    for (int m = 0; m < 2; ++m)
      #pragma unroll
      for (int r = 0; r < 4; ++r) {
        int t = t0 + w * 32 + m * 16 + lgrp * 4 + r;
        if (t < LOUT) out[(size_t)b * LOUT + t] = pd[m][r] / (pnv[m][r] + 1e-12f);
      }
  }
}

// ---------------------------------------------------------------------------

extern "C" void kernel_launch(void* const* d_in, const int* in_sizes, int n_in,
                              void* d_out, int out_size, void* d_ws, size_t ws_size,
                              hipStream_t stream) {
  const float* x     = (const float*)d_in[0];   // (16,16,4096) f32
  const float* E     = (const float*)d_in[1];   // (512,512)    f32
  const float* theta = (const float*)d_in[2];   // (3,9)        f32
  float* out = (float*)d_out;                   // (16,1,1,4089) f32
  (void)d_ws; (void)ws_size;

  w1_kernel<<<QDIM, 256, 0, stream>>>(E, theta);    // -> g_B (W1)
  mm1_kernel<<<QDIM, 256, 0, stream>>>(E, theta);   // g_B -> g_C (W2)
  mm2_kernel<<<QDIM, 256, 0, stream>>>(E, theta);   // g_C -> g_Ah/g_Al (A)
  quadA_kernel<<<dim3(NB, 32), 256, 0, stream>>>(x, out);
}

// Round 20
// 61.577 us; speedup vs baseline: 1.1596x; 1.1596x over previous
//
#include <hip/hip_runtime.h>
#include <math.h>

// Problem constants
#define QDIM 512     // 2^9 state dim
#define DD   128     // K*C_IN = input dim of quadratic form
#define LIN  4096
#define LOUT 4089    // (4096 - 7 - 1)/1 + 1
#define NC   16      // C_IN
#define NB   16      // batch

typedef __attribute__((ext_vector_type(8))) short bf16x8;
typedef __attribute__((ext_vector_type(4))) float f32x4;

// Scratch in device globals (NOT d_ws) — R5 lesson. Every element rewritten
// each call before read. R8+R11: no grid barriers. R19 lesson: Q-path, not
// A-path — formq (2us + edge) buys a 4x reduction in quad MFMA work
// (6.4 vs 25.7 GFLOP). R18 lesson: cooperative LDS staging at 4 blocks/CU.
__device__ float  g_B[QDIM * DD];          // W1 / A (ping-pong) f32
__device__ float  g_C[QDIM * DD];          // W2 f32
__device__ unsigned short g_Qh[DD * DD];   // bf16 hi part of Q
__device__ unsigned short g_Ql[DD * DD];   // bf16 residual of Q

// ---- bf16 helpers (RNE) ----
__device__ __forceinline__ unsigned short f2bf(float f) {
  union { float f; unsigned u; } v; v.f = f;
  unsigned u = v.u + 0x7FFFu + ((v.u >> 16) & 1u);
  return (unsigned short)(u >> 16);
}
__device__ __forceinline__ float bf2f(unsigned short h) {
  union { unsigned u; float f; } v; v.u = ((unsigned)h) << 16;
  return v.f;
}

// ---------------------------------------------------------------------------
// Precompute (verbatim R9, measured-good). Row i of E*R*W = (R^T e_i)^T W.
// ---------------------------------------------------------------------------
__device__ __forceinline__ void butterfly_T(float* col, const float* theta,
                                            int l, int p) {
  #pragma unroll
  for (int qq = 0; qq < 9; ++qq) {
    int q = 8 - qq;                    // reverse order for transpose
    float half = theta[l * 9 + q] * 0.5f;
    float c = cosf(half), s = sinf(half);
    int right = QDIM >> (q + 1);
    int a = p >> (8 - q);
    int r = p & (right - 1);
    int i0 = (a * 2) * right + r;
    int i1 = i0 + right;
    float v0 = col[i0], v1 = col[i1];
    col[i0] = c * v0 + s * v1;         // transposed 2x2
    col[i1] = c * v1 - s * v0;
    __syncthreads();
  }
}

// W1[i][j] = (R1^T e_i)[j], j<128  -> g_B
__global__ __launch_bounds__(256) void w1_kernel(const float* __restrict__ E,
                                                 const float* __restrict__ theta) {
  __shared__ float erow[QDIM];
  int i = blockIdx.x;
  int p = threadIdx.x;
  erow[p]       = E[i * QDIM + p];
  erow[p + 256] = E[i * QDIM + p + 256];
  __syncthreads();
  butterfly_T(erow, theta, 0, p);
  if (p < DD) g_B[i * DD + p] = erow[p];
}

// dst[i][:] = (R_l^T e_i)^T * src.  sel: 0 = g_B->g_C, 1 = g_C->g_B.
__global__ __launch_bounds__(256) void mm_fused_kernel(const float* __restrict__ E,
                                                       const float* __restrict__ theta,
                                                       int l, int sel) {
  const float* W = sel ? g_C : g_B;
  float* D       = sel ? g_B : g_C;
  __shared__ float erow[QDIM];
  __shared__ float part[DD];
  int i = blockIdx.x;
  int tid = threadIdx.x;
  erow[tid]       = E[i * QDIM + tid];
  erow[tid + 256] = E[i * QDIM + tid + 256];
  __syncthreads();
  butterfly_T(erow, theta, l, tid);

  int j = tid & 127, h = tid >> 7;
  float a0 = 0.f, a1 = 0.f, a2 = 0.f, a3 = 0.f;
  int m0 = h * 256;
  #pragma unroll 8
  for (int m = m0; m < m0 + 256; m += 4) {
    a0 = fmaf(erow[m + 0], W[(m + 0) * DD + j], a0);
    a1 = fmaf(erow[m + 1], W[(m + 1) * DD + j], a1);
    a2 = fmaf(erow[m + 2], W[(m + 2) * DD + j], a2);
    a3 = fmaf(erow[m + 3], W[(m + 3) * DD + j], a3);
  }
  float sum = (a0 + a1) + (a2 + a3);
  if (h == 1) part[j] = sum;
  __syncthreads();
  if (h == 0) D[i * DD + j] = sum + part[j];
}

// Q[j1][j2] = sum_i sgn(i) A[i][j1] A[i][j2]; A = g_B. Emit bf16 hi/lo.
__global__ __launch_bounds__(256) void formq_kernel() {
  const float* A = g_B;
  __shared__ float colA[QDIM];
  __shared__ float part[DD];
  int j1 = blockIdx.x;
  int tid = threadIdx.x;
  int j2 = tid & 127, h = tid >> 7;
  for (int i = tid; i < QDIM; i += 256) {
    float sgn = (i < 256) ? 1.0f : -1.0f;
    colA[i] = sgn * A[i * DD + j1];
  }
  __syncthreads();
  float a0 = 0.f, a1 = 0.f, a2 = 0.f, a3 = 0.f;
  int i0 = h * 256;
  #pragma unroll 8
  for (int i = i0; i < i0 + 256; i += 4) {
    a0 = fmaf(colA[i + 0], A[(i + 0) * DD + j2], a0);
    a1 = fmaf(colA[i + 1], A[(i + 1) * DD + j2], a1);
    a2 = fmaf(colA[i + 2], A[(i + 2) * DD + j2], a2);
    a3 = fmaf(colA[i + 3], A[(i + 3) * DD + j2], a3);
  }
  float sum = (a0 + a1) + (a2 + a3);
  if (h == 1) part[j2] = sum;
  __syncthreads();
  if (h == 0) {
    sum += part[j2];
    unsigned short hi = f2bf(sum);
    unsigned short lo = f2bf(sum - bf2f(hi));
    g_Qh[j1 * DD + j2] = hi;
    g_Ql[j1 * DD + j2] = lo;
  }
}

// ---------------------------------------------------------------------------
// quadQ: R9's quad math (bitwise-identical per-t order) with Qh staged in
// LDS (32KB, XOR-swizzled, ONE barrier) and Ql streamed from L2 (1 of 3
// operand reads; L1-shared across the block's 4 waves). 64-t tiles, 1024
// blocks, 4/CU (LDS 37.4KB). absmax canary: 4.882812e-4.
// ---------------------------------------------------------------------------
__global__ __launch_bounds__(256, 4) void quadQ_kernel(const float* __restrict__ x,
                                                       float* __restrict__ out) {
  __shared__ float xs[NC][72];                 // 71 used (64 t + 7 halo)
  __shared__ unsigned short sh_full[DD * DD];  // Qh, 32 KB, swizzled
  int b = blockIdx.x;
  int t0 = blockIdx.y * 64;
  int tid = threadIdx.x;
  int lane = tid & 63;
  int w = tid >> 6;                            // wave: t-rows [w*16, w*16+16)
  const float* xb = x + (size_t)b * NC * LIN;

  for (int idx = tid; idx < NC * 71; idx += 256) {
    int c = idx / 71, o = idx % 71;
    int g = t0 + o;
    xs[c][o] = (g < LIN) ? xb[c * LIN + g] : 0.0f;
  }
  // stage Qh (2048 granules of 8 u16), XOR swizzle: u16col ^= (row&7)<<3
  #pragma unroll
  for (int it = 0; it < 8; ++it) {
    int flat = it * 256 + tid;
    int row = flat >> 4;                       // 0..127
    int g8 = flat & 15;
    int lidx = row * DD + ((g8 * 8) ^ ((row & 7) << 3));
    *(bf16x8*)&sh_full[lidx] = *(const bf16x8*)(g_Qh + row * DD + g8 * 8);
  }
  __syncthreads();

  int lrow = lane & 15;
  int lgrp = lane >> 4;

  f32x4 acc[8];
  #pragma unroll
  for (int n = 0; n < 8; ++n) acc[n] = (f32x4){0.f, 0.f, 0.f, 0.f};

  #pragma unroll
  for (int kb = 0; kb < 4; ++kb) {
    int c = kb * 4 + lgrp;
    int tl = w * 16 + lrow;
    bf16x8 a_hi, a_lo;
    #pragma unroll
    for (int e = 0; e < 8; ++e) {
      float v = xs[c][tl + e];
      unsigned short hh = f2bf(v);
      unsigned short ll = f2bf(v - bf2f(hh));
      a_hi[e] = (short)hh;
      a_lo[e] = (short)ll;
    }
    #pragma unroll
    for (int n = 0; n < 8; ++n) {
      int row = n * 16 + lrow;
      int col = kb * 32 + lgrp * 8;
      bf16x8 b_hi = *(const bf16x8*)&sh_full[row * DD + (col ^ ((row & 7) << 3))];
      bf16x8 b_lo = *(const bf16x8*)(g_Ql + row * DD + col);
      acc[n] = __builtin_amdgcn_mfma_f32_16x16x32_bf16(a_hi, b_hi, acc[n], 0, 0, 0);
      acc[n] = __builtin_amdgcn_mfma_f32_16x16x32_bf16(a_hi, b_lo, acc[n], 0, 0, 0);
      acc[n] = __builtin_amdgcn_mfma_f32_16x16x32_bf16(a_lo, b_hi, acc[n], 0, 0, 0);
    }
  }

  // Epilogue (verbatim R9): dot with v and ||v||^2, 16-lane reduce.
  float pd[4] = {0.f, 0.f, 0.f, 0.f};
  float pn[4] = {0.f, 0.f, 0.f, 0.f};
  #pragma unroll
  for (int n = 0; n < 8; ++n) {
    int i = n * 16 + lrow;
    int cc = i >> 3, ko = i & 7;
    #pragma unroll
    for (int r = 0; r < 4; ++r) {
      int tl = w * 16 + lgrp * 4 + r;
      float v = xs[cc][tl + ko];
      pd[r] = fmaf(acc[n][r], v, pd[r]);
      pn[r] = fmaf(v, v, pn[r]);
    }
  }
  #pragma unroll
  for (int r = 0; r < 4; ++r) {
    #pragma unroll
    for (int m = 1; m < 16; m <<= 1) {
      pd[r] += __shfl_xor(pd[r], m);
      pn[r] += __shfl_xor(pn[r], m);
    }
  }
  if (lrow == 0) {
    #pragma unroll
    for (int r = 0; r < 4; ++r) {
      int t = t0 + w * 16 + lgrp * 4 + r;
      if (t < LOUT) out[(size_t)b * LOUT + t] = pd[r] / (pn[r] + 1e-12f);
    }
  }
}

// ---------------------------------------------------------------------------

extern "C" void kernel_launch(void* const* d_in, const int* in_sizes, int n_in,
                              void* d_out, int out_size, void* d_ws, size_t ws_size,
                              hipStream_t stream) {
  const float* x     = (const float*)d_in[0];   // (16,16,4096) f32
  const float* E     = (const float*)d_in[1];   // (512,512)    f32
  const float* theta = (const float*)d_in[2];   // (3,9)        f32
  float* out = (float*)d_out;                   // (16,1,1,4089) f32
  (void)d_ws; (void)ws_size;

  w1_kernel<<<QDIM, 256, 0, stream>>>(E, theta);              // -> g_B (W1)
  mm_fused_kernel<<<QDIM, 256, 0, stream>>>(E, theta, 1, 0);  // g_B -> g_C
  mm_fused_kernel<<<QDIM, 256, 0, stream>>>(E, theta, 2, 1);  // g_C -> g_B (A)
  formq_kernel<<<DD, 256, 0, stream>>>();                     // g_B -> g_Qh/g_Ql
  quadQ_kernel<<<dim3(NB, 64), 256, 0, stream>>>(x, out);
}